// Round 7
// baseline (1445.782 us; speedup 1.0000x reference)
//
#include <hip/hip_runtime.h>
#include <hip/hip_bf16.h>

typedef __attribute__((ext_vector_type(4))) float f32x4;

// ---------------- degree count ----------------
__global__ void count_kernel(const int* __restrict__ dst, int* __restrict__ cnt, int E) {
    int i = blockIdx.x * blockDim.x + threadIdx.x;
    if (i < E) atomicAdd(&cnt[dst[i]], 1);
}

// ---------------- scan1: block-local exclusive scan + dis = 1/sqrt(deg+1) ----------
__global__ void scan1_kernel(const int* __restrict__ cnt, int* __restrict__ offs,
                             int* __restrict__ bsums, float* __restrict__ dis, int n) {
    const int t = threadIdx.x, lane = t & 63, w = t >> 6;
    const int base = blockIdx.x * 1024 + t * 4;
    int v0 = (base + 0 < n) ? cnt[base + 0] : 0;
    int v1 = (base + 1 < n) ? cnt[base + 1] : 0;
    int v2 = (base + 2 < n) ? cnt[base + 2] : 0;
    int v3 = (base + 3 < n) ? cnt[base + 3] : 0;
    if (base + 0 < n) dis[base + 0] = (float)(1.0 / sqrt((double)(v0 + 1)));
    if (base + 1 < n) dis[base + 1] = (float)(1.0 / sqrt((double)(v1 + 1)));
    if (base + 2 < n) dis[base + 2] = (float)(1.0 / sqrt((double)(v2 + 1)));
    if (base + 3 < n) dis[base + 3] = (float)(1.0 / sqrt((double)(v3 + 1)));
    int s = v0 + v1 + v2 + v3;
    int incl = s;
    #pragma unroll
    for (int off = 1; off < 64; off <<= 1) {
        int y = __shfl_up(incl, off);
        if (lane >= off) incl += y;
    }
    __shared__ int wsum[4];
    if (lane == 63) wsum[w] = incl;
    __syncthreads();
    int wbase = 0;
    #pragma unroll
    for (int k = 0; k < 4; ++k) if (k < w) wbase += wsum[k];
    int run = wbase + incl - s;
    if (base + 0 < n) offs[base + 0] = run; run += v0;
    if (base + 1 < n) offs[base + 1] = run; run += v1;
    if (base + 2 < n) offs[base + 2] = run; run += v2;
    if (base + 3 < n) offs[base + 3] = run;
    if (t == 255) bsums[blockIdx.x] = wbase + incl;
}

__global__ void scan2_kernel(int* __restrict__ bsums, int nb) {
    const int t = threadIdx.x, lane = t & 63, w = t >> 6;  // 128 threads
    int s = (t < nb) ? bsums[t] : 0;
    int incl = s;
    #pragma unroll
    for (int off = 1; off < 64; off <<= 1) {
        int y = __shfl_up(incl, off);
        if (lane >= off) incl += y;
    }
    __shared__ int wsum[2];
    if (lane == 63) wsum[w] = incl;
    __syncthreads();
    int wbase = (w == 1) ? wsum[0] : 0;
    if (t < nb) bsums[t] = wbase + incl - s;
}

// scan3: finalize offsets; emit cursor and packed (start,cnt) meta
__global__ void scan3_kernel(const int* __restrict__ offs, const int* __restrict__ bsums,
                             const int* __restrict__ cnt, int* __restrict__ cursor,
                             int2* __restrict__ meta, int n) {
    int i = blockIdx.x * blockDim.x + threadIdx.x;
    if (i < n) {
        int v = offs[i] + bsums[i >> 10];
        cursor[i] = v;
        meta[i] = make_int2(v, cnt[i]);
    }
}

// ---------------- CSR fill ----------------
__global__ void fill_kernel(const int* __restrict__ src, const int* __restrict__ dst,
                            const float* __restrict__ dis, int* __restrict__ cursor,
                            int* __restrict__ csr_src, float* __restrict__ csr_norm, int E) {
    int i = blockIdx.x * blockDim.x + threadIdx.x;
    if (i < E) {
        int s = src[i], d = dst[i];
        int pos = atomicAdd(&cursor[d], 1);
        csr_src[pos] = s;
        csr_norm[pos] = dis[s] * dis[d];
    }
}

// =============== Layer 1: [N,2] -> [N,16]. One wave per node, W in VGPR. ==========
__global__ __launch_bounds__(256, 4)
void gcn_l1(const float* __restrict__ x, const int2* __restrict__ meta,
            const int* __restrict__ csr_src, const float* __restrict__ csr_norm,
            const float* __restrict__ dis, const float* __restrict__ W,
            const float* __restrict__ B, float* __restrict__ h1, int n, int nwaves) {
    const int lane = threadIdx.x & 63;
    const int wid = blockIdx.x * (blockDim.x >> 6) + (threadIdx.x >> 6);
    const int chunk = (n + nwaves - 1) / nwaves;
    const int n0 = wid * chunk, n1 = min(n0 + chunk, n);
    const int o = lane & 15;
    const float w0 = W[o], w1 = W[16 + o], bo = B[o];
    for (int node = n0; node < n1; ++node) {
        const int2 mt = meta[node];
        const int start = mt.x, m = mt.y;
        float a0 = 0.f, a1 = 0.f;
        for (int j = lane; j < m; j += 64) {
            const int s2 = csr_src[start + j];
            const float nm = csr_norm[start + j];
            const float2 hv = *(const float2*)(x + 2 * (size_t)s2);
            a0 = fmaf(nm, hv.x, a0);
            a1 = fmaf(nm, hv.y, a1);
        }
        #pragma unroll
        for (int off = 32; off >= 1; off >>= 1) {
            a0 += __shfl_xor(a0, off);
            a1 += __shfl_xor(a1, off);
        }
        const float d0 = dis[node], nms = d0 * d0;
        const float2 hs = *(const float2*)(x + 2 * (size_t)node);
        a0 = fmaf(nms, hs.x, a0);
        a1 = fmaf(nms, hs.y, a1);
        if (lane < 16) {
            const float v = fmaf(a0, w0, fmaf(a1, w1, bo));
            h1[(size_t)node * 16 + o] = fmaxf(v, 0.f);
        }
    }
}

// =============== Layer 2: [N,16] -> [N,32]. One wave per node, k split 2-way. ======
__global__ __launch_bounds__(256, 4)
void gcn_l2(const float* __restrict__ h1, const int2* __restrict__ meta,
            const int* __restrict__ csr_src, const float* __restrict__ csr_norm,
            const float* __restrict__ dis, const float* __restrict__ W,
            const float* __restrict__ B, float* __restrict__ h2, int n, int nwaves) {
    const int lane = threadIdx.x & 63;
    const int wid = blockIdx.x * (blockDim.x >> 6) + (threadIdx.x >> 6);
    const int chunk = (n + nwaves - 1) / nwaves;
    const int n0 = wid * chunk, n1 = min(n0 + chunk, n);
    const int o = lane & 31;     // output column
    const int kh = lane >> 5;    // k-half (0: k=0..7, 1: k=8..15)
    float w[8];
    #pragma unroll
    for (int i = 0; i < 8; ++i) w[i] = W[(kh * 8 + i) * 32 + o];
    const float bo = (kh == 0) ? B[o] : 0.f;   // bias only in one half (folded later)
    const int c = lane & 3;      // channel group (4 floats of 16)
    const int sub = lane >> 2;   // edge slot 0..15
    for (int node = n0; node < n1; ++node) {
        const int2 mt = meta[node];
        const int start = mt.x, m = mt.y;
        float ax = 0.f, ay = 0.f, az = 0.f, aw = 0.f;
        for (int j = sub; j < m; j += 32) {   // 2 x 16 slots per batch
            const int jj1 = j + 16;
            const bool ok1 = jj1 < m;
            const int e0 = start + j;
            const int e1 = start + (ok1 ? jj1 : j);
            const int ss0 = csr_src[e0];
            const int ss1 = csr_src[e1];
            const float nn0 = csr_norm[e0];
            const float nn1 = ok1 ? csr_norm[e1] : 0.f;
            f32x4 hv0, hv1;
            const float* p0 = h1 + (size_t)ss0 * 16 + c * 4;
            const float* p1 = h1 + (size_t)ss1 * 16 + c * 4;
            asm volatile("global_load_dwordx4 %0, %1, off" : "=v"(hv0) : "v"(p0) : "memory");
            asm volatile("global_load_dwordx4 %0, %1, off" : "=v"(hv1) : "v"(p1) : "memory");
            asm volatile("s_waitcnt vmcnt(0)" ::: "memory");
            __builtin_amdgcn_sched_barrier(0);
            ax = fmaf(nn0, hv0.x, ax); ay = fmaf(nn0, hv0.y, ay);
            az = fmaf(nn0, hv0.z, az); aw = fmaf(nn0, hv0.w, aw);
            ax = fmaf(nn1, hv1.x, ax); ay = fmaf(nn1, hv1.y, ay);
            az = fmaf(nn1, hv1.z, az); aw = fmaf(nn1, hv1.w, aw);
        }
        #pragma unroll
        for (int off = 32; off >= 4; off >>= 1) {
            ax += __shfl_xor(ax, off); ay += __shfl_xor(ay, off);
            az += __shfl_xor(az, off); aw += __shfl_xor(aw, off);
        }
        const float d0 = dis[node], nms = d0 * d0;
        const f32x4 hs = *(const f32x4*)(h1 + (size_t)node * 16 + c * 4);
        ax = fmaf(nms, hs.x, ax); ay = fmaf(nms, hs.y, ay);
        az = fmaf(nms, hs.z, az); aw = fmaf(nms, hs.w, aw);
        // gather the 8 agg values this lane's k-half needs (groups 2kh, 2kh+1)
        const int s0 = 2 * kh, s1 = 2 * kh + 1;
        float v = bo;
        v = fmaf(__shfl(ax, s0), w[0], v);
        v = fmaf(__shfl(ay, s0), w[1], v);
        v = fmaf(__shfl(az, s0), w[2], v);
        v = fmaf(__shfl(aw, s0), w[3], v);
        v = fmaf(__shfl(ax, s1), w[4], v);
        v = fmaf(__shfl(ay, s1), w[5], v);
        v = fmaf(__shfl(az, s1), w[6], v);
        v = fmaf(__shfl(aw, s1), w[7], v);
        v += __shfl_xor(v, 32);   // fold the two k-halves
        if (lane < 32) h2[(size_t)node * 32 + o] = fmaxf(v, 0.f);
    }
}

// =============== Layer 3: [N,32] -> [N,64]. One wave per node, W in VGPR (32). =====
__global__ __launch_bounds__(256, 4)
void gcn_l3(const float* __restrict__ h2, const int2* __restrict__ meta,
            const int* __restrict__ csr_src, const float* __restrict__ csr_norm,
            const float* __restrict__ dis, const float* __restrict__ W,
            const float* __restrict__ B, float* __restrict__ h3, int n, int nwaves) {
    __shared__ float sAgg[4][32];
    const int lane = threadIdx.x & 63;
    const int wv = threadIdx.x >> 6;
    const int wid = blockIdx.x * (blockDim.x >> 6) + wv;
    const int chunk = (n + nwaves - 1) / nwaves;
    const int n0 = wid * chunk, n1 = min(n0 + chunk, n);
    const int o = lane;          // 64 outputs
    float w[32];
    #pragma unroll
    for (int k = 0; k < 32; ++k) w[k] = W[k * 64 + o];
    const float bo = B[o];
    const int c = lane & 7;      // channel group
    const int sub = lane >> 3;   // edge slot 0..7
    for (int node = n0; node < n1; ++node) {
        const int2 mt = meta[node];
        const int start = mt.x, m = mt.y;
        float ax = 0.f, ay = 0.f, az = 0.f, aw = 0.f;
        for (int j = sub; j < m; j += 32) {   // 4 x 8 slots per batch
            int ss[4]; float nn[4];
            #pragma unroll
            for (int u = 0; u < 4; ++u) {
                const int jj = j + u * 8;
                const bool ok = jj < m;
                const int e = start + (ok ? jj : j);
                ss[u] = csr_src[e];
                nn[u] = ok ? csr_norm[e] : 0.f;
            }
            f32x4 hv[4];
            const float* ap[4];
            #pragma unroll
            for (int u = 0; u < 4; ++u) ap[u] = h2 + (size_t)ss[u] * 32 + c * 4;
            #pragma unroll
            for (int u = 0; u < 4; ++u)
                asm volatile("global_load_dwordx4 %0, %1, off" : "=v"(hv[u]) : "v"(ap[u]) : "memory");
            asm volatile("s_waitcnt vmcnt(0)" ::: "memory");
            __builtin_amdgcn_sched_barrier(0);
            #pragma unroll
            for (int u = 0; u < 4; ++u) {
                ax = fmaf(nn[u], hv[u].x, ax); ay = fmaf(nn[u], hv[u].y, ay);
                az = fmaf(nn[u], hv[u].z, az); aw = fmaf(nn[u], hv[u].w, aw);
            }
        }
        #pragma unroll
        for (int off = 32; off >= 8; off >>= 1) {
            ax += __shfl_xor(ax, off); ay += __shfl_xor(ay, off);
            az += __shfl_xor(az, off); aw += __shfl_xor(aw, off);
        }
        const float d0 = dis[node], nms = d0 * d0;
        const f32x4 hs = *(const f32x4*)(h2 + (size_t)node * 32 + c * 4);
        ax = fmaf(nms, hs.x, ax); ay = fmaf(nms, hs.y, ay);
        az = fmaf(nms, hs.z, az); aw = fmaf(nms, hs.w, aw);
        if (lane < 8) {
            f32x4 t; t.x = ax; t.y = ay; t.z = az; t.w = aw;
            *(f32x4*)&sAgg[wv][lane * 4] = t;
        }
        asm volatile("s_waitcnt lgkmcnt(0)" ::: "memory");
        __builtin_amdgcn_sched_barrier(0);   // rule #18: pin reads below the wait
        float v = bo;
        #pragma unroll
        for (int kq = 0; kq < 8; ++kq) {
            const f32x4 a4 = *(const f32x4*)&sAgg[wv][kq * 4];
            v = fmaf(a4.x, w[4 * kq + 0], v);
            v = fmaf(a4.y, w[4 * kq + 1], v);
            v = fmaf(a4.z, w[4 * kq + 2], v);
            v = fmaf(a4.w, w[4 * kq + 3], v);
        }
        h3[(size_t)node * 64 + o] = fmaxf(v, 0.f);
        asm volatile("s_waitcnt lgkmcnt(0)" ::: "memory");  // reads done before next write
    }
}

// =============== Layer 4: [N,64] -> pooled[G,128]. 2-wave block per node. ==========
__global__ __launch_bounds__(128, 4)
void gcn_l4(const float* __restrict__ h3, const int2* __restrict__ meta,
            const int* __restrict__ csr_src, const float* __restrict__ csr_norm,
            const float* __restrict__ dis, const float* __restrict__ W,
            const float* __restrict__ B, const int* __restrict__ batchv,
            float* __restrict__ pooled, int n, int nblocks) {
    __shared__ float sP[2][64];
    const int wv = threadIdx.x >> 6;     // 0/1
    const int lane = threadIdx.x & 63;
    const int o = lane + 64 * wv;        // output column 0..127
    float w[64];
    #pragma unroll
    for (int k = 0; k < 64; ++k) w[k] = W[k * 128 + o];
    const float bo = B[o];
    const int chunk = (n + nblocks - 1) / nblocks;
    const int n0 = blockIdx.x * chunk, n1 = min(n0 + chunk, n);
    const int c = lane & 15;
    const int slot = wv * 4 + (lane >> 4);   // 0..7 across the 2 waves
    int curg = -1;
    float run = 0.f;
    for (int node = n0; node < n1; ++node) {
        const int2 mt = meta[node];
        const int start = mt.x, m = mt.y;
        float ax = 0.f, ay = 0.f, az = 0.f, aw = 0.f;
        for (int j = slot; j < m; j += 32) {   // 4 x 8 slots per batch
            int ss[4]; float nn[4];
            #pragma unroll
            for (int u = 0; u < 4; ++u) {
                const int jj = j + u * 8;
                const bool ok = jj < m;
                const int e = start + (ok ? jj : j);
                ss[u] = csr_src[e];
                nn[u] = ok ? csr_norm[e] : 0.f;
            }
            f32x4 hv[4];
            const float* ap[4];
            #pragma unroll
            for (int u = 0; u < 4; ++u) ap[u] = h3 + (size_t)ss[u] * 64 + c * 4;
            #pragma unroll
            for (int u = 0; u < 4; ++u)
                asm volatile("global_load_dwordx4 %0, %1, off" : "=v"(hv[u]) : "v"(ap[u]) : "memory");
            asm volatile("s_waitcnt vmcnt(0)" ::: "memory");
            __builtin_amdgcn_sched_barrier(0);
            #pragma unroll
            for (int u = 0; u < 4; ++u) {
                ax = fmaf(nn[u], hv[u].x, ax); ay = fmaf(nn[u], hv[u].y, ay);
                az = fmaf(nn[u], hv[u].z, az); aw = fmaf(nn[u], hv[u].w, aw);
            }
        }
        #pragma unroll
        for (int off = 32; off >= 16; off >>= 1) {
            ax += __shfl_xor(ax, off); ay += __shfl_xor(ay, off);
            az += __shfl_xor(az, off); aw += __shfl_xor(aw, off);
        }
        if (wv == 0) {   // self-loop added by wave 0 only
            const float d0 = dis[node], nms = d0 * d0;
            const f32x4 hs = *(const f32x4*)(h3 + (size_t)node * 64 + c * 4);
            ax = fmaf(nms, hs.x, ax); ay = fmaf(nms, hs.y, ay);
            az = fmaf(nms, hs.z, az); aw = fmaf(nms, hs.w, aw);
        }
        if (lane < 16) {
            f32x4 t; t.x = ax; t.y = ay; t.z = az; t.w = aw;
            *(f32x4*)&sP[wv][lane * 4] = t;
        }
        __syncthreads();
        float v = bo;
        #pragma unroll
        for (int kq = 0; kq < 16; ++kq) {
            const f32x4 a0 = *(const f32x4*)&sP[0][kq * 4];
            const f32x4 a1 = *(const f32x4*)&sP[1][kq * 4];
            v = fmaf(a0.x + a1.x, w[4 * kq + 0], v);
            v = fmaf(a0.y + a1.y, w[4 * kq + 1], v);
            v = fmaf(a0.z + a1.z, w[4 * kq + 2], v);
            v = fmaf(a0.w + a1.w, w[4 * kq + 3], v);
        }
        const float r = fmaxf(v, 0.f);
        const int g = batchv[node];
        if (g != curg) {
            if (curg >= 0)
                atomicMax((int*)&pooled[(size_t)curg * 128 + o], __float_as_int(run));
            curg = g;
            run = r;
        } else {
            run = fmaxf(run, r);
        }
        __syncthreads();   // sP reads complete before next node overwrites
    }
    if (curg >= 0)
        atomicMax((int*)&pooled[(size_t)curg * 128 + o], __float_as_int(run));
}

// ---------------- MLP head: relu(pooled @ W5 + b5) @ W6 + b6 ----------------
__global__ void mlp_kernel(const float* __restrict__ pooled,
                           const float* __restrict__ W5, const float* __restrict__ b5,
                           const float* __restrict__ W6, const float* __restrict__ b6,
                           float* __restrict__ out) {
    const int g = blockIdx.x;
    const int t = threadIdx.x;  // 64 threads
    __shared__ float row[128];
    __shared__ float hid[64];
    row[t] = pooled[g * 128 + t];
    row[64 + t] = pooled[g * 128 + 64 + t];
    __syncthreads();
    float v = b5[t];
    #pragma unroll 8
    for (int c = 0; c < 128; ++c) v = fmaf(row[c], W5[c * 64 + t], v);
    hid[t] = fmaxf(v, 0.f);
    __syncthreads();
    if (t < 10) {
        float o = b6[t];
        #pragma unroll 8
        for (int c = 0; c < 64; ++c) o = fmaf(hid[c], W6[c * 10 + t], o);
        out[g * 10 + t] = o;
    }
}

extern "C" void kernel_launch(void* const* d_in, const int* in_sizes, int n_in,
                              void* d_out, int out_size, void* d_ws, size_t ws_size,
                              hipStream_t stream) {
    const float* x     = (const float*)d_in[0];
    const int*   ei    = (const int*)d_in[1];
    const int*   batch = (const int*)d_in[2];
    const float* W1 = (const float*)d_in[3];  const float* b1 = (const float*)d_in[4];
    const float* W2 = (const float*)d_in[5];  const float* b2 = (const float*)d_in[6];
    const float* W3 = (const float*)d_in[7];  const float* b3 = (const float*)d_in[8];
    const float* W4 = (const float*)d_in[9];  const float* b4 = (const float*)d_in[10];
    const float* W5 = (const float*)d_in[11]; const float* b5 = (const float*)d_in[12];
    const float* W6 = (const float*)d_in[13]; const float* b6 = (const float*)d_in[14];
    float* out = (float*)d_out;

    const int N = in_sizes[0] / 2;       // 100000
    const int E = in_sizes[1] / 2;       // 1600000
    const int G = out_size / 10;         // 512
    const int* src = ei;
    const int* dst = ei + E;

    // workspace layout
    char* p = (char*)d_ws;
    auto take = [&](size_t bytes) -> void* {
        void* r = (void*)p;
        p += (bytes + 255) & ~(size_t)255;
        return r;
    };
    int*   cnt      = (int*)take((size_t)N * 4);
    int*   offs     = (int*)take((size_t)N * 4);
    int*   cursor   = (int*)take((size_t)N * 4);
    int*   bsums    = (int*)take(512 * 4);
    float* dis      = (float*)take((size_t)N * 4);
    int2*  meta     = (int2*)take((size_t)N * 8);
    int*   csr_src  = (int*)take((size_t)E * 4);
    float* csr_norm = (float*)take((size_t)E * 4);
    float* h1       = (float*)take((size_t)N * 16 * 4);
    float* h2       = (float*)take((size_t)N * 32 * 4);
    float* h3       = (float*)take((size_t)N * 64 * 4);
    float* pooled   = (float*)take((size_t)G * 128 * 4);

    hipMemsetAsync(cnt, 0, (size_t)N * 4, stream);
    hipMemsetAsync(pooled, 0, (size_t)G * 128 * 4, stream);

    count_kernel<<<(E + 255) / 256, 256, 0, stream>>>(dst, cnt, E);

    const int NB = (N + 1023) / 1024;    // 98
    scan1_kernel<<<NB, 256, 0, stream>>>(cnt, offs, bsums, dis, N);
    scan2_kernel<<<1, 128, 0, stream>>>(bsums, NB);
    scan3_kernel<<<(N + 255) / 256, 256, 0, stream>>>(offs, bsums, cnt, cursor, meta, N);

    fill_kernel<<<(E + 255) / 256, 256, 0, stream>>>(src, dst, dis, cursor, csr_src, csr_norm, E);

    const int LBLK = 2048;               // 256-thr blocks, 4 waves each
    const int NWAVES = LBLK * 4;         // wave-per-node layers
    gcn_l1<<<LBLK, 256, 0, stream>>>(x,  meta, csr_src, csr_norm, dis, W1, b1, h1, N, NWAVES);
    gcn_l2<<<LBLK, 256, 0, stream>>>(h1, meta, csr_src, csr_norm, dis, W2, b2, h2, N, NWAVES);
    gcn_l3<<<LBLK, 256, 0, stream>>>(h2, meta, csr_src, csr_norm, dis, W3, b3, h3, N, NWAVES);

    const int PBLK = 2048;               // 128-thr blocks, node-pair waves
    gcn_l4<<<PBLK, 128, 0, stream>>>(h3, meta, csr_src, csr_norm, dis, W4, b4, batch, pooled, N, PBLK);

    mlp_kernel<<<G, 64, 0, stream>>>(pooled, W5, b5, W6, b6, out);
}